// Round 9
// baseline (122.901 us; speedup 1.0000x reference)
//
#include <hip/hip_runtime.h>
#include <hip/hip_bf16.h>
#include <stdint.h>

#define B_ROWS 6144
#define N_ROWS 12288
#define DIM 256
#define NCLASS 512
#define NCHUNK 16
#define JCHUNK (N_ROWS / NCHUNK)   // 768
#define NITER (JCHUNK / 32)        // 24 (even)
#define MREP 4
#define ITILE 256                  // 4 waves * 64 rows
#define NITILE (N_ROWS / ITILE)    // 48 -> grid 768 = 3 blocks/CU queued
#define SCALE 14.426950408889634f  // log2(e)/0.1
#define PRESCALE 3.798282432f      // sqrt(SCALE); folded into embeddings
#define CPB 2
#define NCBLK (NCLASS / CPB)       // 256 classum blocks
#define WLCAP 256
#define PREPBLK (N_ROWS / 4)       // 3072 prep blocks

typedef float f32x4 __attribute__((ext_vector_type(4)));
typedef __bf16 bf16x8 __attribute__((ext_vector_type(8)));
typedef __bf16 bf16x4 __attribute__((ext_vector_type(4)));

// ---- workspace layout (bytes) ----
// ebf: swizzled bf16 of sqrt(SCALE)*normalized rows. Panel p = row>>4 (8 KB):
//   elem(row,d) = p*4096 + (d>>5)*512 + ((d>>3)&3)*128 + (row&15)*8 + (d&7)
#define WS_EBF  ((size_t)0)
#define WS_PS   ((size_t)(N_ROWS * DIM * 2))              // 6,291,456
#define WS_LOSS (WS_PS + (size_t)N_ROWS * NCHUNK * 4)     // + 786,432
#define WS_PSUM (WS_LOSS + (size_t)N_ROWS * 4)            // + 49,152

__device__ inline void gload_lds16(const void* g, void* l) {
  __builtin_amdgcn_global_load_lds(
      (const __attribute__((address_space(1))) unsigned int*)g,
      (__attribute__((address_space(3))) unsigned int*)l, 16, 0, 0);
}

__device__ inline float block_sum_256(float v, float* sbuf) {
#pragma unroll
  for (int off = 32; off; off >>= 1) v += __shfl_down(v, off);
  const int lane = threadIdx.x & 63;
  const int w = threadIdx.x >> 6;
  __syncthreads();
  if (lane == 0) sbuf[w] = v;
  __syncthreads();
  return sbuf[0] + sbuf[1] + sbuf[2] + sbuf[3];
}

// Kernel A (merged): blocks [0, NCBLK) = class-major positive term;
// blocks [NCBLK, ...) = prep (normalize*sqrt(SCALE) -> swizzled bf16).
__global__ __launch_bounds__(256) void prep_classum_kernel(
    const float* __restrict__ o1, const float* __restrict__ o2,
    const long long* __restrict__ lab64, __bf16* __restrict__ ebf,
    float* __restrict__ psum) {
  __shared__ short labsh[N_ROWS];          // 24 KB
  __shared__ unsigned short wl[WLCAP];
  __shared__ int woff[4];
  __shared__ int cntsh[CPB];
  __shared__ float spart[4][CPB][DIM];     // 8 KB
  __shared__ float sbuf[4];
  const int tid = threadIdx.x;
  const int lane = tid & 63;
  const int wv = tid >> 6;

  if (blockIdx.x >= NCBLK) {
    const int row = (blockIdx.x - NCBLK) * 4 + wv;
    const float* src = (row < B_ROWS) ? (o1 + (size_t)row * DIM)
                                      : (o2 + (size_t)(row - B_ROWS) * DIM);
    const float4 v = ((const float4*)src)[lane];
    float ss = v.x * v.x + v.y * v.y + v.z * v.z + v.w * v.w;
#pragma unroll
    for (int off = 1; off < 64; off <<= 1) ss += __shfl_xor(ss, off);
    const float rn = PRESCALE / fmaxf(sqrtf(ss), 1e-12f);
    bf16x4 h;
    h[0] = (__bf16)(v.x * rn); h[1] = (__bf16)(v.y * rn);
    h[2] = (__bf16)(v.z * rn); h[3] = (__bf16)(v.w * rn);
    const int p = row >> 4, r = row & 15;
    *(bf16x4*)(ebf + (size_t)p * 4096 + (lane >> 3) * 512 + ((lane >> 1) & 3) * 128
               + r * 8 + (lane & 1) * 4) = h;
    return;
  }

  // ---- classum (exact fp32; unaffected by PRESCALE) ----
  const int cbase = blockIdx.x * CPB;

  for (int k = tid; k < N_ROWS; k += 256) {
    const int lr = (k < B_ROWS) ? k : k - B_ROWS;
    labsh[k] = (short)lab64[lr];
  }
  __syncthreads();

  int mycnt = 0;
  for (int k = tid; k < N_ROWS; k += 256)
    mycnt += ((unsigned)((int)labsh[k] - cbase) < (unsigned)CPB) ? 1 : 0;
  int pre = mycnt;
#pragma unroll
  for (int off = 1; off < 64; off <<= 1) {
    const int o = __shfl_up(pre, off);
    if (lane >= off) pre += o;
  }
  if (lane == 63) woff[wv] = pre;
  __syncthreads();
  int wbase = 0;
#pragma unroll
  for (int i = 0; i < 4; ++i) wbase += (i < wv) ? woff[i] : 0;
  int n = woff[0] + woff[1] + woff[2] + woff[3];
  if (n > WLCAP) n = WLCAP;
  int o = wbase + pre - mycnt;
  for (int k = tid; k < N_ROWS; k += 256) {
    if ((unsigned)((int)labsh[k] - cbase) < (unsigned)CPB) {
      if (o < WLCAP) wl[o] = (unsigned short)k;
      ++o;
    }
  }
  __syncthreads();

  if (wv < CPB) {
    int cc = 0;
    for (int u = lane; u < n; u += 64) cc += ((int)labsh[wl[u]] - cbase == wv) ? 1 : 0;
#pragma unroll
    for (int off = 1; off < 64; off <<= 1) cc += __shfl_xor(cc, off);
    if (lane == 0) cntsh[wv] = cc;
  }

  float4 a0 = {0.f, 0.f, 0.f, 0.f}, a1 = {0.f, 0.f, 0.f, 0.f};
  for (int u = wv; u < n; u += 4) {
    const int row = wl[u];
    const int c = (int)labsh[row] - cbase;
    const float* src = (row < B_ROWS) ? (o1 + (size_t)row * DIM)
                                      : (o2 + (size_t)(row - B_ROWS) * DIM);
    const float4 v = ((const float4*)src)[lane];
    float ss = v.x * v.x + v.y * v.y + v.z * v.z + v.w * v.w;
#pragma unroll
    for (int off = 1; off < 64; off <<= 1) ss += __shfl_xor(ss, off);
    const float r = 1.0f / fmaxf(sqrtf(ss), 1e-12f);
    const float m0 = (c == 0) ? r : 0.f;
    const float m1 = (c == 1) ? r : 0.f;
    a0.x += v.x * m0; a0.y += v.y * m0; a0.z += v.z * m0; a0.w += v.w * m0;
    a1.x += v.x * m1; a1.y += v.y * m1; a1.z += v.z * m1; a1.w += v.w * m1;
  }
  *(float4*)&spart[wv][0][lane * 4] = a0;
  *(float4*)&spart[wv][1][lane * 4] = a1;
  __syncthreads();

  float rr[CPB];
#pragma unroll
  for (int c = 0; c < CPB; ++c) {
    const float s = spart[0][c][tid] + spart[1][c][tid]
                  + spart[2][c][tid] + spart[3][c][tid];
    rr[c] = block_sum_256(s * s, sbuf);
  }
  if (tid == 0) {
    float p = 0.f;
#pragma unroll
    for (int c = 0; c < CPB; ++c)
      p += (cntsh[c] > 0) ? rr[c] / (float)cntsh[c] : 0.f;
    psum[blockIdx.x] = p;
  }
}

// Kernel B: streaming Sexp per i-row. MREP=4 (64 rows/wave), 3-buffer
// counted-vmcnt pipeline + double-banked acc: exp2 of tile t-1 overlaps
// MFMA of tile t (separate pipes, no dependency).
#define LSE_BODY(T, ACCC, ACCP)                                               \
  {                                                                           \
    const int t_ = (T);                                                       \
    if (t_ + 2 < NITER) {                                                     \
      const char* gs = gsrc0 + (size_t)(t_ + 2) * 16384;                      \
      char* ldst = smem + ((bsel + 2) % 3) * 16384 + w * 1024;                \
      _Pragma("unroll")                                                       \
      for (int q = 0; q < 4; ++q) gload_lds16(gs + q * 4096, ldst + q * 4096);\
    }                                                                         \
    const char* lb = smem + bsel * 16384 + lane * 16;                         \
    _Pragma("unroll")                                                         \
    for (int m = 0; m < MREP; ++m) {                                          \
      ACCC[m][0] = (f32x4){0.f, 0.f, 0.f, 0.f};                               \
      ACCC[m][1] = (f32x4){0.f, 0.f, 0.f, 0.f};                               \
    }                                                                         \
    __builtin_amdgcn_s_setprio(1);                                            \
    _Pragma("unroll")                                                         \
    for (int kc = 0; kc < 8; ++kc) {                                          \
      const bf16x8 b0 = *(const bf16x8*)(lb + kc * 1024);                     \
      const bf16x8 b1 = *(const bf16x8*)(lb + kc * 1024 + 8192);              \
      _Pragma("unroll")                                                       \
      for (int m = 0; m < MREP; ++m) {                                        \
        ACCC[m][0] = __builtin_amdgcn_mfma_f32_16x16x32_bf16(a[m][kc], b0, ACCC[m][0], 0, 0, 0); \
        ACCC[m][1] = __builtin_amdgcn_mfma_f32_16x16x32_bf16(a[m][kc], b1, ACCC[m][1], 0, 0, 0); \
      }                                                                       \
    }                                                                         \
    __builtin_amdgcn_s_setprio(0);                                            \
    _Pragma("unroll")                                                         \
    for (int m = 0; m < MREP; ++m)                                            \
      _Pragma("unroll")                                                       \
      for (int r = 0; r < 4; ++r)                                             \
        s[m][r] += __builtin_amdgcn_exp2f(ACCP[m][0][r])                      \
                 + __builtin_amdgcn_exp2f(ACCP[m][1][r]);                     \
    __builtin_amdgcn_sched_barrier(0);                                        \
    asm volatile("s_waitcnt lgkmcnt(0)" ::: "memory");                        \
    if (t_ + 2 < NITER) {                                                     \
      asm volatile("s_waitcnt vmcnt(4)" ::: "memory");                        \
    } else {                                                                  \
      asm volatile("s_waitcnt vmcnt(0)" ::: "memory");                        \
    }                                                                         \
    __builtin_amdgcn_sched_barrier(0);                                        \
    __builtin_amdgcn_s_barrier();                                             \
    __builtin_amdgcn_sched_barrier(0);                                        \
    bsel = (bsel + 1) % 3;                                                    \
  }

__global__ __launch_bounds__(256, 2) void lse_kernel(const __bf16* __restrict__ ebf,
                                                     float* __restrict__ ps) {
  __shared__ __align__(16) char smem[3 * 16384];
  const int bid = blockIdx.x;
  const int itile = bid / NCHUNK;
  const int chunk = bid - itile * NCHUNK;
  const int i0 = itile * ITILE;
  const int jbase = chunk * JCHUNK;
  const int tid = threadIdx.x;
  const int lane = tid & 63;
  const int w = tid >> 6;
  const char* const base = (const char*)ebf;

  // A fragments: wave w owns panels (i0>>4) + w*4 + m
  bf16x8 a[MREP][8];
  {
    const char* ap = base + (size_t)((i0 >> 4) + w * MREP) * 8192 + lane * 16;
#pragma unroll
    for (int m = 0; m < MREP; ++m)
#pragma unroll
      for (int kc = 0; kc < 8; ++kc)
        a[m][kc] = *(const bf16x8*)(ap + m * 8192 + kc * 1024);
  }

  float s[MREP][4];
  f32x4 acc0[MREP][2], acc1[MREP][2];
#pragma unroll
  for (int m = 0; m < MREP; ++m) {
#pragma unroll
    for (int r = 0; r < 4; ++r) s[m][r] = 0.0f;
    acc1[m][0] = (f32x4){-1e30f, -1e30f, -1e30f, -1e30f};  // exp2 -> 0
    acc1[m][1] = (f32x4){-1e30f, -1e30f, -1e30f, -1e30f};
  }

  const char* gsrc0 = base + (size_t)(jbase >> 4) * 8192 + w * 1024 + lane * 16;

#pragma unroll
  for (int q = 0; q < 4; ++q)
    gload_lds16(gsrc0 + q * 4096, smem + w * 1024 + q * 4096);
#pragma unroll
  for (int q = 0; q < 4; ++q)
    gload_lds16(gsrc0 + 16384 + q * 4096, smem + 16384 + w * 1024 + q * 4096);
  __syncthreads();

  int bsel = 0;
#pragma unroll 1
  for (int t2 = 0; t2 < NITER; t2 += 2) {
    LSE_BODY(t2, acc0, acc1);       // MFMA -> acc0; exp2(acc1) overlapped
    LSE_BODY(t2 + 1, acc1, acc0);   // MFMA -> acc1; exp2(acc0) overlapped
  }
  // final tile (NITER-1, odd) sits in acc1
#pragma unroll
  for (int m = 0; m < MREP; ++m)
#pragma unroll
    for (int r = 0; r < 4; ++r)
      s[m][r] += __builtin_amdgcn_exp2f(acc1[m][0][r])
               + __builtin_amdgcn_exp2f(acc1[m][1][r]);

#pragma unroll
  for (int off = 1; off < 16; off <<= 1)
#pragma unroll
    for (int m = 0; m < MREP; ++m)
#pragma unroll
      for (int r = 0; r < 4; ++r)
        s[m][r] += __shfl_xor(s[m][r], off);

  if ((lane & 15) == 0) {
    const int g = lane >> 4;
#pragma unroll
    for (int m = 0; m < MREP; ++m)
#pragma unroll
      for (int r = 0; r < 4; ++r) {
        const int i = i0 + w * 64 + m * 16 + g * 4 + r;
        ps[(size_t)i * NCHUNK + chunk] = s[m][r];
      }
  }
}

// Kernel C: loss[row] = log(sum_chunk ps). One thread per row.
__global__ __launch_bounds__(256) void finish_kernel(const float* __restrict__ ps,
                                                     float* __restrict__ loss) {
  const int row = blockIdx.x * 256 + threadIdx.x;
  const float4 s0 = ((const float4*)(ps + (size_t)row * NCHUNK))[0];
  const float4 s1 = ((const float4*)(ps + (size_t)row * NCHUNK))[1];
  const float4 s2 = ((const float4*)(ps + (size_t)row * NCHUNK))[2];
  const float4 s3 = ((const float4*)(ps + (size_t)row * NCHUNK))[3];
  const float sm = (s0.x + s0.y + s0.z + s0.w) + (s1.x + s1.y + s1.z + s1.w)
                 + (s2.x + s2.y + s2.z + s2.w) + (s3.x + s3.y + s3.z + s3.w);
  loss[row] = logf(sm);
}

// Kernel D: deterministic mean: (sum LSE)/N - 10*(sum psum)/N.
__global__ __launch_bounds__(256) void mean_kernel(const float* __restrict__ loss,
                                                   const float* __restrict__ psum,
                                                   float* __restrict__ out) {
  __shared__ float sbuf[4];
  float v = 0.0f;
  for (int i = threadIdx.x; i < N_ROWS; i += 256) v += loss[i];
  const float vs = block_sum_256(v, sbuf);
  const float qs = block_sum_256(psum[threadIdx.x], sbuf);
  if (threadIdx.x == 0)
    out[0] = vs * (1.0f / (float)N_ROWS) - qs * (10.0f / (float)N_ROWS);
}

extern "C" void kernel_launch(void* const* d_in, const int* in_sizes, int n_in,
                              void* d_out, int out_size, void* d_ws, size_t ws_size,
                              hipStream_t stream) {
  const float* o1 = (const float*)d_in[0];
  const float* o2 = (const float*)d_in[1];
  const long long* labels = (const long long*)d_in[2];
  char* ws = (char*)d_ws;
  __bf16* ebf = (__bf16*)(ws + WS_EBF);
  float* ps = (float*)(ws + WS_PS);
  float* loss = (float*)(ws + WS_LOSS);
  float* psum = (float*)(ws + WS_PSUM);

  prep_classum_kernel<<<NCBLK + PREPBLK, 256, 0, stream>>>(o1, o2, labels, ebf, psum);
  lse_kernel<<<NITILE * NCHUNK, 256, 0, stream>>>(ebf, ps);
  finish_kernel<<<N_ROWS / 256, 256, 0, stream>>>(ps, loss);
  mean_kernel<<<1, 256, 0, stream>>>(loss, psum, (float*)d_out);
}

// Round 10
// 99.135 us; speedup vs baseline: 1.2397x; 1.2397x over previous
//
#include <hip/hip_runtime.h>
#include <hip/hip_bf16.h>
#include <stdint.h>

#define B_ROWS 6144
#define N_ROWS 12288
#define DIM 256
#define NCLASS 512
#define NCHUNK 12
#define JCHUNK (N_ROWS / NCHUNK)   // 1024
#define NITER (JCHUNK / 32)        // 32
#define MREP 3
#define ITILE 192                  // 4 waves * 48 rows
#define NITILE (N_ROWS / ITILE)    // 64 -> grid 768
#define SCALE 14.426950408889634f  // log2(e)/0.1
#define PRESCALE 3.798282432f      // sqrt(SCALE); folded into embeddings
#define NCBLK NCLASS               // 512 classum blocks, 1 class each
#define WLCAP 128                  // n ~ Binom(12288,1/512): mean 24, 21 sigma
#define PREPBLK (N_ROWS / 4)       // 3072 prep blocks

typedef float f32x4 __attribute__((ext_vector_type(4)));
typedef __bf16 bf16x8 __attribute__((ext_vector_type(8)));
typedef __bf16 bf16x4 __attribute__((ext_vector_type(4)));

// ---- workspace layout (bytes) ----
// ebf: swizzled bf16 of sqrt(SCALE)*normalized rows. Panel p = row>>4 (8 KB):
//   elem(row,d) = p*4096 + (d>>5)*512 + ((d>>3)&3)*128 + (row&15)*8 + (d&7)
#define WS_EBF  ((size_t)0)
#define WS_PS   ((size_t)(N_ROWS * DIM * 2))              // 6,291,456
#define WS_LOSS (WS_PS + (size_t)N_ROWS * NCHUNK * 4)     // + 589,824
#define WS_PSUM (WS_LOSS + (size_t)N_ROWS * 4)            // + 49,152

__device__ inline void gload_lds16(const void* g, void* l) {
  __builtin_amdgcn_global_load_lds(
      (const __attribute__((address_space(1))) unsigned int*)g,
      (__attribute__((address_space(3))) unsigned int*)l, 16, 0, 0);
}

__device__ inline float block_sum_256(float v, float* sbuf) {
#pragma unroll
  for (int off = 32; off; off >>= 1) v += __shfl_down(v, off);
  const int lane = threadIdx.x & 63;
  const int w = threadIdx.x >> 6;
  __syncthreads();
  if (lane == 0) sbuf[w] = v;
  __syncthreads();
  return sbuf[0] + sbuf[1] + sbuf[2] + sbuf[3];
}

// Kernel A (merged): blocks [0, NCBLK) = class-major positive term (1 class
// per block, bitmask compact, no label LDS); blocks [NCBLK, ...) = prep.
__global__ __launch_bounds__(256) void prep_classum_kernel(
    const float* __restrict__ o1, const float* __restrict__ o2,
    const long long* __restrict__ lab64, __bf16* __restrict__ ebf,
    float* __restrict__ psum) {
  __shared__ unsigned short wl[WLCAP];
  __shared__ int woff[4];
  __shared__ float spart[4][DIM];   // 4 KB
  __shared__ float sbuf[4];
  const int tid = threadIdx.x;
  const int lane = tid & 63;
  const int wv = tid >> 6;

  if (blockIdx.x >= NCBLK) {
    // ---- prep: wave per row, normalize*sqrt(SCALE), swizzled bf16 store ----
    const int row = (blockIdx.x - NCBLK) * 4 + wv;
    const float* src = (row < B_ROWS) ? (o1 + (size_t)row * DIM)
                                      : (o2 + (size_t)(row - B_ROWS) * DIM);
    const float4 v = ((const float4*)src)[lane];
    float ss = v.x * v.x + v.y * v.y + v.z * v.z + v.w * v.w;
#pragma unroll
    for (int off = 1; off < 64; off <<= 1) ss += __shfl_xor(ss, off);
    const float rn = PRESCALE / fmaxf(sqrtf(ss), 1e-12f);
    bf16x4 h;
    h[0] = (__bf16)(v.x * rn); h[1] = (__bf16)(v.y * rn);
    h[2] = (__bf16)(v.z * rn); h[3] = (__bf16)(v.w * rn);
    const int p = row >> 4, r = row & 15;
    *(bf16x4*)(ebf + (size_t)p * 4096 + (lane >> 3) * 512 + ((lane >> 1) & 3) * 128
               + r * 8 + (lane & 1) * 4) = h;
    return;
  }

  // ---- classum: block owns class c; psum[c] = ||S_c||^2 / n ----
  const int c = blockIdx.x;

  // pass 1: one label sweep, register bitmask of matches (48 its < 64 bits)
  unsigned long long bits = 0ull;
  int mycnt = 0;
#pragma unroll
  for (int it = 0; it < N_ROWS / 256; ++it) {
    const int k = tid + it * 256;
    const int lr = (k < B_ROWS) ? k : k - B_ROWS;
    if ((int)lab64[lr] == c) { bits |= (1ull << it); ++mycnt; }
  }
  // inclusive scan within wave
  int pre = mycnt;
#pragma unroll
  for (int off = 1; off < 64; off <<= 1) {
    const int o = __shfl_up(pre, off);
    if (lane >= off) pre += o;
  }
  if (lane == 63) woff[wv] = pre;
  __syncthreads();
  int wbase = 0;
#pragma unroll
  for (int i = 0; i < 4; ++i) wbase += (i < wv) ? woff[i] : 0;
  int n = woff[0] + woff[1] + woff[2] + woff[3];
  if (n > WLCAP) n = WLCAP;
  // compact from bitmask at deterministic offsets
  int o = wbase + pre - mycnt;
#pragma unroll
  for (int it = 0; it < N_ROWS / 256; ++it) {
    if ((bits >> it) & 1ull) {
      if (o < WLCAP) wl[o] = (unsigned short)(tid + it * 256);
      ++o;
    }
  }
  __syncthreads();

  // wave-parallel accumulate (self-normalizing), fixed order -> deterministic
  float4 a = {0.f, 0.f, 0.f, 0.f};
  for (int u = wv; u < n; u += 4) {
    const int row = wl[u];
    const float* src = (row < B_ROWS) ? (o1 + (size_t)row * DIM)
                                      : (o2 + (size_t)(row - B_ROWS) * DIM);
    const float4 v = ((const float4*)src)[lane];
    float ss = v.x * v.x + v.y * v.y + v.z * v.z + v.w * v.w;
#pragma unroll
    for (int off = 1; off < 64; off <<= 1) ss += __shfl_xor(ss, off);
    const float r = 1.0f / fmaxf(sqrtf(ss), 1e-12f);
    a.x += v.x * r; a.y += v.y * r; a.z += v.z * r; a.w += v.w * r;
  }
  *(float4*)&spart[wv][lane * 4] = a;
  __syncthreads();

  const float s = spart[0][tid] + spart[1][tid] + spart[2][tid] + spart[3][tid];
  const float r2 = block_sum_256(s * s, sbuf);
  if (tid == 0) psum[c] = (n > 0) ? r2 / (float)n : 0.f;
}

// Kernel B: streaming Sexp per i-row via MFMA bf16. MREP=3, 3-buffer
// counted-vmcnt pipeline (T3+T4) + setprio. Proven 71 us structure (R8);
// only change: SCALE folded into ebf, epilogue is exp2(acc) directly.
__global__ __launch_bounds__(256, 3) void lse_kernel(const __bf16* __restrict__ ebf,
                                                     float* __restrict__ ps) {
  __shared__ __align__(16) char smem[3 * 16384];
  const int bid = blockIdx.x;
  const int itile = bid / NCHUNK;
  const int chunk = bid - itile * NCHUNK;
  const int i0 = itile * ITILE;
  const int jbase = chunk * JCHUNK;
  const int tid = threadIdx.x;
  const int lane = tid & 63;
  const int w = tid >> 6;
  const char* const base = (const char*)ebf;

  bf16x8 a[MREP][8];
  {
    const char* ap = base + (size_t)((i0 >> 4) + w * MREP) * 8192 + lane * 16;
#pragma unroll
    for (int m = 0; m < MREP; ++m)
#pragma unroll
      for (int kc = 0; kc < 8; ++kc)
        a[m][kc] = *(const bf16x8*)(ap + m * 8192 + kc * 1024);
  }

  float s[MREP][4];
#pragma unroll
  for (int m = 0; m < MREP; ++m)
#pragma unroll
    for (int r = 0; r < 4; ++r) s[m][r] = 0.0f;

  const char* gsrc0 = base + (size_t)(jbase >> 4) * 8192 + w * 1024 + lane * 16;

#pragma unroll
  for (int q = 0; q < 4; ++q)
    gload_lds16(gsrc0 + q * 4096, smem + w * 1024 + q * 4096);
#pragma unroll
  for (int q = 0; q < 4; ++q)
    gload_lds16(gsrc0 + 16384 + q * 4096, smem + 16384 + w * 1024 + q * 4096);
  __syncthreads();

  int bsel = 0;
  for (int t = 0; t < NITER; ++t) {
    if (t + 2 < NITER) {
      const char* gs = gsrc0 + (size_t)(t + 2) * 16384;
      char* ldst = smem + ((bsel + 2) % 3) * 16384 + w * 1024;
#pragma unroll
      for (int q = 0; q < 4; ++q) gload_lds16(gs + q * 4096, ldst + q * 4096);
    }

    const char* lb = smem + bsel * 16384 + lane * 16;
    f32x4 acc[MREP][2];
#pragma unroll
    for (int m = 0; m < MREP; ++m) {
      acc[m][0] = (f32x4){0.0f, 0.0f, 0.0f, 0.0f};
      acc[m][1] = (f32x4){0.0f, 0.0f, 0.0f, 0.0f};
    }
    __builtin_amdgcn_s_setprio(1);
#pragma unroll
    for (int kc = 0; kc < 8; ++kc) {
      const bf16x8 b0 = *(const bf16x8*)(lb + kc * 1024);
      const bf16x8 b1 = *(const bf16x8*)(lb + kc * 1024 + 8192);
#pragma unroll
      for (int m = 0; m < MREP; ++m) {
        acc[m][0] = __builtin_amdgcn_mfma_f32_16x16x32_bf16(a[m][kc], b0, acc[m][0], 0, 0, 0);
        acc[m][1] = __builtin_amdgcn_mfma_f32_16x16x32_bf16(a[m][kc], b1, acc[m][1], 0, 0, 0);
      }
    }
    __builtin_amdgcn_s_setprio(0);
    // epilogue: s += exp2(acc); SCALE pre-folded, sim*SCALE bounded by 14.43
#pragma unroll
    for (int m = 0; m < MREP; ++m)
#pragma unroll
      for (int r = 0; r < 4; ++r)
        s[m][r] += __builtin_amdgcn_exp2f(acc[m][0][r])
                 + __builtin_amdgcn_exp2f(acc[m][1][r]);

    __builtin_amdgcn_sched_barrier(0);
    asm volatile("s_waitcnt lgkmcnt(0)" ::: "memory");
    if (t + 2 < NITER) {
      asm volatile("s_waitcnt vmcnt(4)" ::: "memory");
    } else {
      asm volatile("s_waitcnt vmcnt(0)" ::: "memory");
    }
    __builtin_amdgcn_sched_barrier(0);
    __builtin_amdgcn_s_barrier();
    __builtin_amdgcn_sched_barrier(0);

    bsel = (bsel + 1) % 3;
  }

#pragma unroll
  for (int off = 1; off < 16; off <<= 1)
#pragma unroll
    for (int m = 0; m < MREP; ++m)
#pragma unroll
      for (int r = 0; r < 4; ++r)
        s[m][r] += __shfl_xor(s[m][r], off);

  if ((lane & 15) == 0) {
    const int g = lane >> 4;
#pragma unroll
    for (int m = 0; m < MREP; ++m)
#pragma unroll
      for (int r = 0; r < 4; ++r) {
        const int i = i0 + w * 48 + m * 16 + g * 4 + r;
        ps[(size_t)i * NCHUNK + chunk] = s[m][r];
      }
  }
}

// Kernel C: loss[row] = log(sum_chunk ps). One thread per row.
__global__ __launch_bounds__(256) void finish_kernel(const float* __restrict__ ps,
                                                     float* __restrict__ loss) {
  const int row = blockIdx.x * 256 + threadIdx.x;
  const float4 s0 = ((const float4*)(ps + (size_t)row * NCHUNK))[0];
  const float4 s1 = ((const float4*)(ps + (size_t)row * NCHUNK))[1];
  const float4 s2 = ((const float4*)(ps + (size_t)row * NCHUNK))[2];
  const float sm = (s0.x + s0.y + s0.z + s0.w) + (s1.x + s1.y + s1.z + s1.w)
                 + (s2.x + s2.y + s2.z + s2.w);
  loss[row] = logf(sm);
}

// Kernel D: deterministic mean: (sum LSE)/N - 10*(sum psum)/N.
__global__ __launch_bounds__(256) void mean_kernel(const float* __restrict__ loss,
                                                   const float* __restrict__ psum,
                                                   float* __restrict__ out) {
  __shared__ float sbuf[4];
  float v = 0.0f;
  for (int i = threadIdx.x; i < N_ROWS; i += 256) v += loss[i];
  const float vs = block_sum_256(v, sbuf);
  const float qs = block_sum_256(psum[threadIdx.x] + psum[threadIdx.x + 256], sbuf);
  if (threadIdx.x == 0)
    out[0] = vs * (1.0f / (float)N_ROWS) - qs * (10.0f / (float)N_ROWS);
}

extern "C" void kernel_launch(void* const* d_in, const int* in_sizes, int n_in,
                              void* d_out, int out_size, void* d_ws, size_t ws_size,
                              hipStream_t stream) {
  const float* o1 = (const float*)d_in[0];
  const float* o2 = (const float*)d_in[1];
  const long long* labels = (const long long*)d_in[2];
  char* ws = (char*)d_ws;
  __bf16* ebf = (__bf16*)(ws + WS_EBF);
  float* ps = (float*)(ws + WS_PS);
  float* loss = (float*)(ws + WS_LOSS);
  float* psum = (float*)(ws + WS_PSUM);

  prep_classum_kernel<<<NCBLK + PREPBLK, 256, 0, stream>>>(o1, o2, labels, ebf, psum);
  lse_kernel<<<NITILE * NCHUNK, 256, 0, stream>>>(ebf, ps);
  finish_kernel<<<N_ROWS / 256, 256, 0, stream>>>(ps, loss);
  mean_kernel<<<1, 256, 0, stream>>>(loss, psum, (float*)d_out);
}

// Round 11
// 85.294 us; speedup vs baseline: 1.4409x; 1.1623x over previous
//
#include <hip/hip_runtime.h>
#include <hip/hip_bf16.h>
#include <stdint.h>

#define B_ROWS 6144
#define N_ROWS 12288
#define DIM 256
#define NCLASS 512
#define NCHUNK 12
#define JCHUNK (N_ROWS / NCHUNK)   // 1024
#define NITER (JCHUNK / 32)        // 32
#define MREP 3
#define ITILE 192                  // 4 waves * 48 rows
#define NITILE (N_ROWS / ITILE)    // 64 -> grid 768
#define SCALE 14.426950408889634f  // log2(e)/0.1
#define PRESCALE 3.798282432f      // sqrt(SCALE); folded into embeddings
#define NCBLK NCLASS               // 512 classum blocks, 1 class each
#define WLCAP 128                  // n ~ Binom(12288,1/512): mean 24
#define PREPBLK (N_ROWS / 16)      // 768 prep blocks (16 rows each @1024 thr)
#define FINBLK (N_ROWS / 256)      // 48

typedef float f32x4 __attribute__((ext_vector_type(4)));
typedef __bf16 bf16x8 __attribute__((ext_vector_type(8)));
typedef __bf16 bf16x4 __attribute__((ext_vector_type(4)));

// ---- workspace layout (bytes) ----
// ebf: swizzled bf16 of sqrt(SCALE)*normalized rows. Panel p = row>>4 (8 KB):
//   elem(row,d) = p*4096 + (d>>5)*512 + ((d>>3)&3)*128 + (row&15)*8 + (d&7)
#define WS_EBF  ((size_t)0)
#define WS_PS   ((size_t)(N_ROWS * DIM * 2))              // 6,291,456
#define WS_PSUM (WS_PS + (size_t)N_ROWS * NCHUNK * 4)     // + 589,824
#define WS_PART (WS_PSUM + (size_t)NCLASS * 4)            // + 2,048
#define WS_CNT  (WS_PART + (size_t)FINBLK * 4)            // + 192

__device__ inline void gload_lds16(const void* g, void* l) {
  __builtin_amdgcn_global_load_lds(
      (const __attribute__((address_space(1))) unsigned int*)g,
      (__attribute__((address_space(3))) unsigned int*)l, 16, 0, 0);
}

__device__ inline float block_sum_256(float v, float* sbuf) {
#pragma unroll
  for (int off = 32; off; off >>= 1) v += __shfl_down(v, off);
  const int lane = threadIdx.x & 63;
  const int w = threadIdx.x >> 6;
  __syncthreads();
  if (lane == 0) sbuf[w] = v;
  __syncthreads();
  return sbuf[0] + sbuf[1] + sbuf[2] + sbuf[3];
}

__device__ inline float block_sum_1024(float v, float* sbuf16) {
#pragma unroll
  for (int off = 32; off; off >>= 1) v += __shfl_down(v, off);
  const int lane = threadIdx.x & 63;
  const int w = threadIdx.x >> 6;
  __syncthreads();
  if (lane == 0) sbuf16[w] = v;
  __syncthreads();
  float t = 0.f;
#pragma unroll
  for (int i = 0; i < 16; ++i) t += sbuf16[i];
  return t;
}

// Kernel A (merged, 1024 threads): blocks [0, NCBLK) = class-major positive
// term (1 class/block, bitmask compact, 16-wave accumulate); blocks
// [NCBLK, ...) = prep (16 rows/block: normalize*sqrt(SCALE) -> swizzled bf16).
__global__ __launch_bounds__(1024) void prep_classum_kernel(
    const float* __restrict__ o1, const float* __restrict__ o2,
    const long long* __restrict__ lab64, __bf16* __restrict__ ebf,
    float* __restrict__ psum) {
  __shared__ unsigned short wl[WLCAP];
  __shared__ int woff[16];
  __shared__ float spart[16][DIM];   // 16 KB
  __shared__ float sbuf16[16];
  const int tid = threadIdx.x;
  const int lane = tid & 63;
  const int wv = tid >> 6;           // 0..15

  if (blockIdx.x >= NCBLK) {
    // ---- prep: wave per row ----
    const int row = (blockIdx.x - NCBLK) * 16 + wv;
    const float* src = (row < B_ROWS) ? (o1 + (size_t)row * DIM)
                                      : (o2 + (size_t)(row - B_ROWS) * DIM);
    const float4 v = ((const float4*)src)[lane];
    float ss = v.x * v.x + v.y * v.y + v.z * v.z + v.w * v.w;
#pragma unroll
    for (int off = 1; off < 64; off <<= 1) ss += __shfl_xor(ss, off);
    const float rn = PRESCALE / fmaxf(sqrtf(ss), 1e-12f);
    bf16x4 h;
    h[0] = (__bf16)(v.x * rn); h[1] = (__bf16)(v.y * rn);
    h[2] = (__bf16)(v.z * rn); h[3] = (__bf16)(v.w * rn);
    const int p = row >> 4, r = row & 15;
    *(bf16x4*)(ebf + (size_t)p * 4096 + (lane >> 3) * 512 + ((lane >> 1) & 3) * 128
               + r * 8 + (lane & 1) * 4) = h;
    return;
  }

  // ---- classum: block owns class c; psum[c] = ||S_c||^2 / n ----
  const int c = blockIdx.x;

  // pass 1: label sweep, register bitmask (12 iterations @1024 threads)
  unsigned long long bits = 0ull;
  int mycnt = 0;
#pragma unroll
  for (int it = 0; it < N_ROWS / 1024; ++it) {
    const int k = tid + it * 1024;
    const int lr = (k < B_ROWS) ? k : k - B_ROWS;
    if ((int)lab64[lr] == c) { bits |= (1ull << it); ++mycnt; }
  }
  // inclusive scan within wave, then block offsets across 16 waves
  int pre = mycnt;
#pragma unroll
  for (int off = 1; off < 64; off <<= 1) {
    const int o = __shfl_up(pre, off);
    if (lane >= off) pre += o;
  }
  if (lane == 63) woff[wv] = pre;
  __syncthreads();
  int wbase = 0, n = 0;
#pragma unroll
  for (int i = 0; i < 16; ++i) {
    const int wi = woff[i];
    wbase += (i < wv) ? wi : 0;
    n += wi;
  }
  if (n > WLCAP) n = WLCAP;
  int o = wbase + pre - mycnt;
#pragma unroll
  for (int it = 0; it < N_ROWS / 1024; ++it) {
    if ((bits >> it) & 1ull) {
      if (o < WLCAP) wl[o] = (unsigned short)(tid + it * 1024);
      ++o;
    }
  }
  __syncthreads();

  // wave-parallel accumulate (self-normalizing): wave wv takes u = wv, wv+16..
  float4 a = {0.f, 0.f, 0.f, 0.f};
  for (int u = wv; u < n; u += 16) {
    const int row = wl[u];
    const float* src = (row < B_ROWS) ? (o1 + (size_t)row * DIM)
                                      : (o2 + (size_t)(row - B_ROWS) * DIM);
    const float4 v = ((const float4*)src)[lane];
    float ss = v.x * v.x + v.y * v.y + v.z * v.z + v.w * v.w;
#pragma unroll
    for (int off = 1; off < 64; off <<= 1) ss += __shfl_xor(ss, off);
    const float r = 1.0f / fmaxf(sqrtf(ss), 1e-12f);
    a.x += v.x * r; a.y += v.y * r; a.z += v.z * r; a.w += v.w * r;
  }
  *(float4*)&spart[wv][lane * 4] = a;
  __syncthreads();

  // S_c[d] for d = tid/4 block... reduce 16 wave partials at dim = tid (1024
  // threads cover 256 dims x 4): threads 0..255 own dims; others idle-sum 0.
  float s = 0.f;
  if (tid < DIM) {
#pragma unroll
    for (int i = 0; i < 16; ++i) s += spart[i][tid];
  }
  const float r2 = block_sum_1024(s * s, sbuf16);
  if (tid == 0) psum[c] = (n > 0) ? r2 / (float)n : 0.f;
}

// Kernel B: streaming Sexp per i-row via MFMA bf16. FROZEN (R10, 68 us):
// MREP=3, 3-buffer counted-vmcnt pipeline + setprio, SCALE pre-folded.
__global__ __launch_bounds__(256, 3) void lse_kernel(const __bf16* __restrict__ ebf,
                                                     float* __restrict__ ps) {
  __shared__ __align__(16) char smem[3 * 16384];
  const int bid = blockIdx.x;
  const int itile = bid / NCHUNK;
  const int chunk = bid - itile * NCHUNK;
  const int i0 = itile * ITILE;
  const int jbase = chunk * JCHUNK;
  const int tid = threadIdx.x;
  const int lane = tid & 63;
  const int w = tid >> 6;
  const char* const base = (const char*)ebf;

  bf16x8 a[MREP][8];
  {
    const char* ap = base + (size_t)((i0 >> 4) + w * MREP) * 8192 + lane * 16;
#pragma unroll
    for (int m = 0; m < MREP; ++m)
#pragma unroll
      for (int kc = 0; kc < 8; ++kc)
        a[m][kc] = *(const bf16x8*)(ap + m * 8192 + kc * 1024);
  }

  float s[MREP][4];
#pragma unroll
  for (int m = 0; m < MREP; ++m)
#pragma unroll
    for (int r = 0; r < 4; ++r) s[m][r] = 0.0f;

  const char* gsrc0 = base + (size_t)(jbase >> 4) * 8192 + w * 1024 + lane * 16;

#pragma unroll
  for (int q = 0; q < 4; ++q)
    gload_lds16(gsrc0 + q * 4096, smem + w * 1024 + q * 4096);
#pragma unroll
  for (int q = 0; q < 4; ++q)
    gload_lds16(gsrc0 + 16384 + q * 4096, smem + 16384 + w * 1024 + q * 4096);
  __syncthreads();

  int bsel = 0;
  for (int t = 0; t < NITER; ++t) {
    if (t + 2 < NITER) {
      const char* gs = gsrc0 + (size_t)(t + 2) * 16384;
      char* ldst = smem + ((bsel + 2) % 3) * 16384 + w * 1024;
#pragma unroll
      for (int q = 0; q < 4; ++q) gload_lds16(gs + q * 4096, ldst + q * 4096);
    }

    const char* lb = smem + bsel * 16384 + lane * 16;
    f32x4 acc[MREP][2];
#pragma unroll
    for (int m = 0; m < MREP; ++m) {
      acc[m][0] = (f32x4){0.0f, 0.0f, 0.0f, 0.0f};
      acc[m][1] = (f32x4){0.0f, 0.0f, 0.0f, 0.0f};
    }
    __builtin_amdgcn_s_setprio(1);
#pragma unroll
    for (int kc = 0; kc < 8; ++kc) {
      const bf16x8 b0 = *(const bf16x8*)(lb + kc * 1024);
      const bf16x8 b1 = *(const bf16x8*)(lb + kc * 1024 + 8192);
#pragma unroll
      for (int m = 0; m < MREP; ++m) {
        acc[m][0] = __builtin_amdgcn_mfma_f32_16x16x32_bf16(a[m][kc], b0, acc[m][0], 0, 0, 0);
        acc[m][1] = __builtin_amdgcn_mfma_f32_16x16x32_bf16(a[m][kc], b1, acc[m][1], 0, 0, 0);
      }
    }
    __builtin_amdgcn_s_setprio(0);
#pragma unroll
    for (int m = 0; m < MREP; ++m)
#pragma unroll
      for (int r = 0; r < 4; ++r)
        s[m][r] += __builtin_amdgcn_exp2f(acc[m][0][r])
                 + __builtin_amdgcn_exp2f(acc[m][1][r]);

    __builtin_amdgcn_sched_barrier(0);
    asm volatile("s_waitcnt lgkmcnt(0)" ::: "memory");
    if (t + 2 < NITER) {
      asm volatile("s_waitcnt vmcnt(4)" ::: "memory");
    } else {
      asm volatile("s_waitcnt vmcnt(0)" ::: "memory");
    }
    __builtin_amdgcn_sched_barrier(0);
    __builtin_amdgcn_s_barrier();
    __builtin_amdgcn_sched_barrier(0);

    bsel = (bsel + 1) % 3;
  }

#pragma unroll
  for (int off = 1; off < 16; off <<= 1)
#pragma unroll
    for (int m = 0; m < MREP; ++m)
#pragma unroll
      for (int r = 0; r < 4; ++r)
        s[m][r] += __shfl_xor(s[m][r], off);

  if ((lane & 15) == 0) {
    const int g = lane >> 4;
#pragma unroll
    for (int m = 0; m < MREP; ++m)
#pragma unroll
      for (int r = 0; r < 4; ++r) {
        const int i = i0 + w * 48 + m * 16 + g * 4 + r;
        ps[(size_t)i * NCHUNK + chunk] = s[m][r];
      }
  }
}

// Kernel C (fused finish+mean): 48 blocks; each computes its 256 rows' LSE
// partial sum -> partial[bid]; last-arriving block (monotonic counter, works
// from any initial value) reduces partials + psum -> out[0]. Deterministic:
// partials are fixed values, final sum in fixed order by one block.
__global__ __launch_bounds__(256) void finishmean_kernel(
    const float* __restrict__ ps, const float* __restrict__ psum,
    float* __restrict__ partial, unsigned int* __restrict__ cnt,
    float* __restrict__ out) {
  __shared__ float sbuf[4];
  __shared__ int is_last;
  const int tid = threadIdx.x;
  const int row = blockIdx.x * 256 + tid;
  const float4 s0 = ((const float4*)(ps + (size_t)row * NCHUNK))[0];
  const float4 s1 = ((const float4*)(ps + (size_t)row * NCHUNK))[1];
  const float4 s2 = ((const float4*)(ps + (size_t)row * NCHUNK))[2];
  const float sm = (s0.x + s0.y + s0.z + s0.w) + (s1.x + s1.y + s1.z + s1.w)
                 + (s2.x + s2.y + s2.z + s2.w);
  const float p = block_sum_256(logf(sm), sbuf);
  if (tid == 0) {
    partial[blockIdx.x] = p;
    __threadfence();
    const unsigned int old = atomicAdd(cnt, 1u);
    is_last = ((old % (unsigned)FINBLK) == (unsigned)(FINBLK - 1)) ? 1 : 0;
  }
  __syncthreads();
  if (!is_last) return;
  __threadfence();
  // last block: reduce 48 partials (atomic-RMW reads: coherent cross-XCD)
  float v = (tid < FINBLK) ? atomicAdd(&partial[tid], 0.0f) : 0.0f;
  const float vs = block_sum_256(v, sbuf);
  // psum written by a prior dispatch -> plain loads are coherent
  const float qs = block_sum_256(psum[tid] + psum[tid + 256], sbuf);
  if (tid == 0)
    out[0] = vs * (1.0f / (float)N_ROWS) - qs * (10.0f / (float)N_ROWS);
}

extern "C" void kernel_launch(void* const* d_in, const int* in_sizes, int n_in,
                              void* d_out, int out_size, void* d_ws, size_t ws_size,
                              hipStream_t stream) {
  const float* o1 = (const float*)d_in[0];
  const float* o2 = (const float*)d_in[1];
  const long long* labels = (const long long*)d_in[2];
  char* ws = (char*)d_ws;
  __bf16* ebf = (__bf16*)(ws + WS_EBF);
  float* ps = (float*)(ws + WS_PS);
  float* psum = (float*)(ws + WS_PSUM);
  float* partial = (float*)(ws + WS_PART);
  unsigned int* cnt = (unsigned int*)(ws + WS_CNT);

  prep_classum_kernel<<<NCBLK + PREPBLK, 1024, 0, stream>>>(o1, o2, labels, ebf, psum);
  lse_kernel<<<NITILE * NCHUNK, 256, 0, stream>>>(ebf, ps);
  finishmean_kernel<<<FINBLK, 256, 0, stream>>>(ps, psum, partial, cnt, (float*)d_out);
}